// Round 9
// baseline (13676.672 us; speedup 1.0000x reference)
//
#include <hip/hip_runtime.h>
#include <hip/hip_bf16.h>

// Sizes (fixed): T=512 tokens, D=256 embed, L=256 lstm, H=512 hidden. 4L=1024.

typedef _Float16 h2v __attribute__((ext_vector_type(2)));
typedef unsigned int u32x8 __attribute__((ext_vector_type(8)));

#define BC(x) __builtin_bit_cast(h2v, (x))

__device__ __forceinline__ float fdot2f(h2v a, h2v b, float c) {
#if __has_builtin(__builtin_amdgcn_fdot2)
    return __builtin_amdgcn_fdot2(a, b, c, false);
#else
    return c + (float)a[0] * (float)b[0] + (float)a[1] * (float)b[1];
#endif
}

// Same-XCD L2 channel: sc0 load bypasses L1 and reads the shared XCD L2;
// CDNA L1 is write-through so an sc0 store lands in L2. Used ONLY as an
// accelerator: every value is also published via agent-scope atomics, and
// readers fall back to that path after a bounded number of fast polls, so
// sc0 misbehavior can only cost time, never correctness or a hang.
__device__ __forceinline__ unsigned long long l2_load_u64(
        const unsigned long long* p) {
    unsigned long long v;
    asm volatile("global_load_dwordx2 %0, %1, off sc0\n\ts_waitcnt vmcnt(0)"
                 : "=v"(v)
                 : "v"(p)
                 : "memory");
    return v;
}
__device__ __forceinline__ void l2_store_u64(unsigned long long* p,
                                             unsigned long long v) {
    asm volatile("global_store_dwordx2 %0, %1, off sc0" ::"v"(p), "v"(v)
                 : "memory");
}

// ---------------------------------------------------------------------------
// prep_u: U [256 x 1024] f32 row-major -> packed half2 per (k-pair, col)
// Uf[k2*1024 + col] = (U[2k2][col], U[2k2+1][col]) as 2xf16 in a uint
// ---------------------------------------------------------------------------
__global__ __launch_bounds__(256) void prep_u(const float* __restrict__ U,
                                              unsigned int* __restrict__ Uf) {
    int idx = blockIdx.x * 256 + threadIdx.x;  // < 131072
    int k2 = idx >> 10, col = idx & 1023;
    union { _Float16 h[2]; unsigned int u; } p;
    p.h[0] = (_Float16)U[(2 * k2) * 1024 + col];
    p.h[1] = (_Float16)U[(2 * k2 + 1) * 1024 + col];
    Uf[idx] = p.u;
}

// ---------------------------------------------------------------------------
// Generic f32 GEMM: C[M,N] = opA(A)[M,K] @ B[K,N] + bias[N]
// ---------------------------------------------------------------------------
__global__ __launch_bounds__(256) void gemm_bias(const float* __restrict__ A,
                                                 const float* __restrict__ B,
                                                 const float* __restrict__ bias,
                                                 float* __restrict__ C,
                                                 int M, int N, int K, int revA) {
    __shared__ float sA[16][65];
    __shared__ float sB[16][65];
    int tid = threadIdx.x;
    int bm = blockIdx.y * 64, bn = blockIdx.x * 64;
    int tx = tid & 15, ty = tid >> 4;
    float acc[4][4] = {};
    for (int k0 = 0; k0 < K; k0 += 16) {
#pragma unroll
        for (int l = 0; l < 4; l++) {
            int flat = tid + 256 * l;
            int ml = flat >> 4, kk = flat & 15;
            int row = bm + ml;
            if (revA) row = M - 1 - row;
            sA[kk][ml] = A[row * K + k0 + kk];
        }
#pragma unroll
        for (int l = 0; l < 4; l++) {
            int flat = tid + 256 * l;
            int kk = flat >> 6, nl = flat & 63;
            sB[kk][nl] = B[(k0 + kk) * N + bn + nl];
        }
        __syncthreads();
#pragma unroll
        for (int kk = 0; kk < 16; kk++) {
            float a[4], b[4];
#pragma unroll
            for (int i = 0; i < 4; i++) a[i] = sA[kk][ty + 16 * i];
#pragma unroll
            for (int j = 0; j < 4; j++) b[j] = sB[kk][tx + 16 * j];
#pragma unroll
            for (int i = 0; i < 4; i++)
#pragma unroll
                for (int j = 0; j < 4; j++) acc[i][j] += a[i] * b[j];
        }
        __syncthreads();
    }
#pragma unroll
    for (int i = 0; i < 4; i++) {
        int r = bm + ty + 16 * i;
#pragma unroll
        for (int j = 0; j < 4; j++) {
            int cidx = bn + tx + 16 * j;
            float bv = bias ? bias[cidx] : 0.f;
            C[r * N + cidx] = acc[i][j] + bv;
        }
    }
}

// ---------------------------------------------------------------------------
// lstm_duo: 16 blocks launched; workers {0,8}=dir0, {1,9}=dir1, rest exit.
// (round-robin blockIdx->XCD: 0&8 and 1&9 each expected to share an XCD L2.)
//
// Structure (round 7, proven): block b owns units [128b,128b+128), all 4
// gate columns (col = 256*gate + 128*b + u; 512 cols, 1 col/thread).
// kp[0,64) in LDS (128KB), kp[64,128) in 8 x u32x8 = 64 VGPRs. Dots split
// by h-ownership: Phase A (own-half, no wait) / poll remote / Phase B.
//
// Cross-block exchange, hang-proof + stale-proof (round-9 design):
//  - entry = {hi = 0xA5|epoch|tag, lo = packed f16 h-pair}, parity dbuf.
//  - writer ALWAYS agent-scope-stores to the safe slot (round-5/7 proven
//    channel) and ADDITIONALLY sc0-stores to a fast slot iff the XCC_ID
//    handshake verified same-XCD placement.
//  - reader: bounded fast polls (<=128) then agent-scope fallback with
//    s_sleep backoff. Worst case = round-7 latency, never a hang.
//  - epoch (1=lstm1, 2=lstm2) in the tag: stale L2/LLC lines from the other
//    dispatch can never false-match; same-epoch replay staleness is benign
//    (deterministic identical data).
//  - step 0 skips the poll entirely (h(-1)=0), removing cold-start
//    dependence on memset visibility (the 21-42ms rocprof outlier suspect).
// ---------------------------------------------------------------------------
#define UAq(r) ((r) < 8 ? q0[(r) & 7] : (r) < 16 ? q1[(r) & 7] : \
                (r) < 24 ? q2[(r) & 7] : (r) < 32 ? q3[(r) & 7] : \
                (r) < 40 ? q4[(r) & 7] : (r) < 48 ? q5[(r) & 7] : \
                (r) < 56 ? q6[(r) & 7] : q7[(r) & 7])

// dots over LDS-resident kp [0,64)  <-> h chunks hp4[0..16)  (k in [0,128))
#define DOTS_LDS(accA, accB)                                   \
    _Pragma("unroll") for (int cch = 0; cch < 16; cch++) {     \
        uint4 hc = hp4[cch];                                   \
        const unsigned int* su = &sU[(4 * cch) * 512 + t];     \
        accA = fdot2f(BC(hc.x), BC(su[0]), accA);              \
        accB = fdot2f(BC(hc.y), BC(su[512]), accB);            \
        accA = fdot2f(BC(hc.z), BC(su[1024]), accA);           \
        accB = fdot2f(BC(hc.w), BC(su[1536]), accB);           \
    }

// dots over reg-resident kp [64,128) <-> h chunks hp4[16..32) (k in [128,256))
#define DOTS_REG(accA, accB)                                   \
    _Pragma("unroll") for (int cch = 16; cch < 32; cch++) {    \
        uint4 hc = hp4[cch];                                   \
        const int r0 = 4 * (cch - 16);                         \
        accA = fdot2f(BC(hc.x), BC(UAq(r0 + 0)), accA);        \
        accB = fdot2f(BC(hc.y), BC(UAq(r0 + 1)), accB);        \
        accA = fdot2f(BC(hc.z), BC(UAq(r0 + 2)), accA);        \
        accB = fdot2f(BC(hc.w), BC(UAq(r0 + 3)), accB);        \
    }

__global__ __launch_bounds__(512) void lstm_duo(
        const unsigned int* __restrict__ Ua, const unsigned int* __restrict__ Ub,
        const float* __restrict__ Pa, const float* __restrict__ Pb,
        float* __restrict__ Oa, float* __restrict__ Ob,
        unsigned long long* Hsafe, unsigned long long* Hfast,
        unsigned int* xslot, int epoch) {
    int bid = blockIdx.x;
    int role;  // dir*2 + half
    if (bid == 0) role = 0;
    else if (bid == 8) role = 1;
    else if (bid == 1) role = 2;
    else if (bid == 9) role = 3;
    else return;
    int dir = role >> 1;  // 0 = fwd, 1 = bwd
    int b = role & 1;     // owns hidden units [128b, 128b+128)
    const unsigned int* U = dir ? Ub : Ua;
    const float* P = dir ? Pb : Pa;
    float* O = dir ? Ob : Oa;
    // per dir: 2 parity x 2 halves x 64 tagged entries
    unsigned long long* Hsd = Hsafe + dir * 256;
    unsigned long long* Hfd = Hfast + dir * 256;

    __shared__ unsigned int sU[64 * 512];            // 131072 B, kp-major
    __shared__ __align__(16) unsigned int sH[128];   // h as packed f16 pairs
    __shared__ float sZ[512];
    __shared__ unsigned int sFast;

    int t = threadIdx.x;  // 0..511
    // gate g = t>>7, unit u = t&127; column in the 4L z-vector:
    int col = ((t >> 7) << 8) + (b << 7) + (t & 127);

    // stage kp [0,64) of this block's 512 columns into LDS
    for (int kp = 0; kp < 64; kp++) sU[kp * 512 + t] = U[kp * 1024 + col];

    // kp [64,128) register-resident: 8 x 8-wide SSA vectors = 64 VGPRs
    u32x8 q0, q1, q2, q3, q4, q5, q6, q7;
#pragma unroll
    for (int j = 0; j < 8; j++) {
        q0[j] = U[(64 + j) * 1024 + col];
        q1[j] = U[(72 + j) * 1024 + col];
        q2[j] = U[(80 + j) * 1024 + col];
        q3[j] = U[(88 + j) * 1024 + col];
        q4[j] = U[(96 + j) * 1024 + col];
        q5[j] = U[(104 + j) * 1024 + col];
        q6[j] = U[(112 + j) * 1024 + col];
        q7[j] = U[(120 + j) * 1024 + col];
    }
    asm volatile(""
                 : "+v"(q0), "+v"(q1), "+v"(q2), "+v"(q3),
                   "+v"(q4), "+v"(q5), "+v"(q6), "+v"(q7));

    // XCD handshake: publish own XCC_ID, wait for partner's, compare.
    // Publish-before-spin on both sides => no deadlock (4 workers <= CUs).
    unsigned int xcc;
    asm volatile("s_getreg_b32 %0, hwreg(HW_REG_XCC_ID)" : "=s"(xcc));
    if (t == 0) {
        __hip_atomic_store(&xslot[role], xcc + 1u, __ATOMIC_RELEASE,
                           __HIP_MEMORY_SCOPE_AGENT);
        unsigned int peer;
        do {
            __builtin_amdgcn_s_sleep(1);
            peer = __hip_atomic_load(&xslot[role ^ 1], __ATOMIC_ACQUIRE,
                                     __HIP_MEMORY_SCOPE_AGENT);
        } while (peer == 0u);
        sFast = (peer - 1u == xcc) ? 1u : 0u;
    }

    if (t < 128) sH[t] = 0u;
    float c0 = 0.f, c1 = 0.f;  // gate threads: cell state for units 2t, 2t+1
    __syncthreads();
    const bool fast = (sFast != 0u);
    const unsigned int hi_base = 0xA5000000u | ((unsigned int)epoch << 16);

    const uint4* hp4 = (const uint4*)sH;  // 32 chunks x (4 h2v) = 256 h
    float pc = P[col];
    for (int step = 0; step < 512; step++) {
        float pn = pc;
        if (step < 511) pn = P[(step + 1) * 1024 + col];

        const bool reader = (step > 0) && (t >= 64) && (t < 128);
        int ridx = (step & 1) * 128 + (1 - b) * 64 + (t - 64);
        unsigned long long rv = 0;
        if (reader && !fast) {
            // early probe on the slow channel: issue before Phase A so the
            // compiler can sink the waitcnt past the dot work
            rv = __hip_atomic_load(&Hsd[ridx], __ATOMIC_RELAXED,
                                   __HIP_MEMORY_SCOPE_AGENT);
        }

        // Phase A: own-half dots (own h written locally at end of prev step)
        float a0 = pc, a1 = 0.f;
        if (b == 0) { DOTS_LDS(a0, a1) } else { DOTS_REG(a0, a1) }

        // finish poll, land remote h(step-1) into the other sH half
        if (reader) {
            unsigned int want = hi_base | (unsigned int)step;
            unsigned long long v;
            if (fast) {
                v = l2_load_u64(&Hfd[ridx]);
                int tries = 0;
                while ((unsigned int)(v >> 32) != want && tries < 128) {
                    v = l2_load_u64(&Hfd[ridx]);
                    ++tries;
                }
                // bounded-fallback: the safe channel always works
                while ((unsigned int)(v >> 32) != want) {
                    __builtin_amdgcn_s_sleep(1);
                    v = __hip_atomic_load(&Hsd[ridx], __ATOMIC_RELAXED,
                                          __HIP_MEMORY_SCOPE_AGENT);
                }
            } else {
                v = rv;
                while ((unsigned int)(v >> 32) != want) {
                    __builtin_amdgcn_s_sleep(1);
                    v = __hip_atomic_load(&Hsd[ridx], __ATOMIC_RELAXED,
                                          __HIP_MEMORY_SCOPE_AGENT);
                }
            }
            sH[(1 - b) * 64 + (t - 64)] = (unsigned int)v;
        }
        __syncthreads();

        // Phase B: remote-half dots
        float a2 = 0.f, a3 = 0.f;
        if (b == 0) { DOTS_REG(a2, a3) } else { DOTS_LDS(a2, a3) }

        sZ[t] = (a0 + a1) + (a2 + a3);
        __syncthreads();

        if (t < 64) {  // gates for local units 2t, 2t+1 (single wave)
            float2 z0 = ((const float2*)sZ)[t];          // i
            float2 z1 = ((const float2*)(sZ + 128))[t];  // f
            float2 z2 = ((const float2*)(sZ + 256))[t];  // g
            float2 z3 = ((const float2*)(sZ + 384))[t];  // o
            float ig0 = 1.f / (1.f + __expf(-z0.x));
            float fg0 = 1.f / (1.f + __expf(-z1.x));
            float gg0 = 1.f - 2.f / (1.f + __expf(2.f * z2.x));
            float og0 = 1.f / (1.f + __expf(-z3.x));
            c0 = fg0 * c0 + ig0 * gg0;
            float h0 = og0 * (1.f - 2.f / (1.f + __expf(2.f * c0)));
            float ig1 = 1.f / (1.f + __expf(-z0.y));
            float fg1 = 1.f / (1.f + __expf(-z1.y));
            float gg1 = 1.f - 2.f / (1.f + __expf(2.f * z2.y));
            float og1 = 1.f / (1.f + __expf(-z3.y));
            c1 = fg1 * c1 + ig1 * gg1;
            float h1 = og1 * (1.f - 2.f / (1.f + __expf(2.f * c1)));
            // publish FIRST: propagation overlaps the epilogue + barrier
            union { _Float16 hh[2]; unsigned int u; } pk;
            pk.hh[0] = (_Float16)h0;
            pk.hh[1] = (_Float16)h1;
            unsigned int hi = hi_base | (unsigned int)(step + 1);
            unsigned long long v =
                ((unsigned long long)hi << 32) | (unsigned long long)pk.u;
            int widx = ((step + 1) & 1) * 128 + (b << 6) + t;
            if (fast) l2_store_u64(&Hfd[widx], v);
            __hip_atomic_store(&Hsd[widx], v, __ATOMIC_RELAXED,
                               __HIP_MEMORY_SCOPE_AGENT);
            ((float2*)(O + step * 256 + (b << 7)))[t] = make_float2(h0, h1);
            sH[(b << 6) + t] = pk.u;  // own half locally
        }
        __syncthreads();
        pc = pn;
    }
}

// ---------------------------------------------------------------------------
// concat: V[t][0:256] = F[t], V[t][256:512] = Bk[511-t]
// ---------------------------------------------------------------------------
__global__ __launch_bounds__(256) void concat_k(const float* __restrict__ F,
                                                const float* __restrict__ Bk,
                                                float* __restrict__ V) {
    int idx = blockIdx.x * 256 + threadIdx.x;  // < 262144
    int t = idx >> 9, d = idx & 511;
    V[idx] = (d < 256) ? F[t * 256 + d] : Bk[(511 - t) * 256 + d - 256];
}

// ---------------------------------------------------------------------------
// head: S[i][j] = sum_h tanh(HF[i][h] + MF[j][h]) * w[h] + outBias
// ---------------------------------------------------------------------------
__global__ __launch_bounds__(256) void head_kernel(const float* __restrict__ HF,
                                                   const float* __restrict__ MF,
                                                   const float* __restrict__ w,
                                                   const float* __restrict__ outb,
                                                   float* __restrict__ S) {
    int i = blockIdx.x;
    __shared__ float sHF[512], sW[512];
    int tid = threadIdx.x;
    sHF[tid] = HF[i * 512 + tid];
    sHF[tid + 256] = HF[i * 512 + 256 + tid];
    sW[tid] = w[tid];
    sW[tid + 256] = w[tid + 256];
    __syncthreads();
    int lane = tid & 63, wv = tid >> 6;
    float ob = outb[0];
    for (int j = wv; j < 512; j += 4) {
        const float* mf = MF + j * 512;
        float acc = 0.f;
#pragma unroll
        for (int r = 0; r < 8; r++) {
            int h = lane + 64 * r;
            float x = sHF[h] + mf[h];
            acc += sW[h] * (1.f - 2.f / (1.f + __expf(2.f * x)));
        }
#pragma unroll
        for (int off = 32; off; off >>= 1) acc += __shfl_down(acc, off);
        if (lane == 0) S[i * 512 + j] = acc + ob;
    }
}

// ---------------------------------------------------------------------------
extern "C" void kernel_launch(void* const* d_in, const int* in_sizes, int n_in,
                              void* d_out, int out_size, void* d_ws, size_t ws_size,
                              hipStream_t stream) {
    const float* emb      = (const float*)d_in[0];
    const float* W_f1     = (const float*)d_in[1];
    const float* U_f1     = (const float*)d_in[2];
    const float* b_f1     = (const float*)d_in[3];
    const float* W_b1     = (const float*)d_in[4];
    const float* U_b1     = (const float*)d_in[5];
    const float* b_b1     = (const float*)d_in[6];
    const float* W_f2     = (const float*)d_in[7];
    const float* U_f2     = (const float*)d_in[8];
    const float* b_f2     = (const float*)d_in[9];
    const float* W_b2     = (const float*)d_in[10];
    const float* U_b2     = (const float*)d_in[11];
    const float* b_b2     = (const float*)d_in[12];
    const float* FOH      = (const float*)d_in[13];
    const float* FOM      = (const float*)d_in[14];
    const float* hidBias  = (const float*)d_in[15];
    const float* outLayer = (const float*)d_in[16];
    const float* outBias  = (const float*)d_in[17];
    float* out = (float*)d_out;

    // workspace carve (16 MB total)
    unsigned int* uf = (unsigned int*)d_ws;          // 4 x 131072 uints = 2MB
    unsigned int* uf_f1 = uf;
    unsigned int* uf_b1 = uf + 131072;
    unsigned int* uf_f2 = uf + 262144;
    unsigned int* uf_b2 = uf + 393216;
    float* f = (float*)d_ws + 524288;
    float* P1f = f;                 // 512x1024
    float* P1b = f + 524288;
    float* P2f = f + 1048576;
    float* P2b = f + 1572864;
    float* rf1 = f + 2097152;       // 512x256
    float* rb1 = f + 2228224;
    float* rf2 = f + 2359296;
    float* rb2 = f + 2490368;
    float* v    = f + 2621440;      // 512x512
    float* hcat = f + 2883584;
    float* HFb  = f + 3145728;      // 512x512 (includes hidBias)
    float* MFb  = f + 3407872;
    // sync region aliases MFb (dead during both lstm dispatches).
    // Hsafe: 512 u64 (4KB) | Hfast: 512 u64 (4KB) | xslot: 4 uints.
    unsigned long long* Hsafe = (unsigned long long*)(f + 3407872);
    unsigned long long* Hfast = Hsafe + 512;
    unsigned int* xslot = (unsigned int*)(Hsafe + 1024);

    prep_u<<<512, 256, 0, stream>>>(U_f1, uf_f1);
    prep_u<<<512, 256, 0, stream>>>(U_b1, uf_b1);
    prep_u<<<512, 256, 0, stream>>>(U_f2, uf_f2);
    prep_u<<<512, 256, 0, stream>>>(U_b2, uf_b2);

    dim3 g1(1024 / 64, 512 / 64);
    gemm_bias<<<g1, 256, 0, stream>>>(emb, W_f1, b_f1, P1f, 512, 1024, 256, 0);
    gemm_bias<<<g1, 256, 0, stream>>>(emb, W_b1, b_b1, P1b, 512, 1024, 256, 1);

    hipMemsetAsync(Hsafe, 0, 12288, stream);
    lstm_duo<<<16, 512, 0, stream>>>(uf_f1, uf_b1, P1f, P1b, rf1, rb1,
                                     Hsafe, Hfast, xslot, 1);

    concat_k<<<1024, 256, 0, stream>>>(rf1, rb1, v);

    gemm_bias<<<g1, 256, 0, stream>>>(v, W_f2, b_f2, P2f, 512, 1024, 512, 0);
    gemm_bias<<<g1, 256, 0, stream>>>(v, W_b2, b_b2, P2b, 512, 1024, 512, 1);

    hipMemsetAsync(Hsafe, 0, 12288, stream);
    lstm_duo<<<16, 512, 0, stream>>>(uf_f2, uf_b2, P2f, P2b, rf2, rb2,
                                     Hsafe, Hfast, xslot, 2);

    concat_k<<<1024, 256, 0, stream>>>(rf2, rb2, hcat);

    dim3 g2(512 / 64, 512 / 64);
    gemm_bias<<<g2, 256, 0, stream>>>(hcat, FOH, hidBias, HFb, 512, 512, 512, 0);
    gemm_bias<<<g2, 256, 0, stream>>>(hcat, FOM, nullptr, MFb, 512, 512, 512, 0);

    head_kernel<<<512, 256, 0, stream>>>(HFb, MFb, outLayer, outBias, out);
}

// Round 10
// 2843.520 us; speedup vs baseline: 4.8098x; 4.8098x over previous
//
#include <hip/hip_runtime.h>
#include <hip/hip_bf16.h>

// Sizes (fixed): T=512 tokens, D=256 embed, L=256 lstm, H=512 hidden. 4L=1024.

typedef _Float16 h2v __attribute__((ext_vector_type(2)));
typedef unsigned int u32x8 __attribute__((ext_vector_type(8)));

#define BC(x) __builtin_bit_cast(h2v, (x))

__device__ __forceinline__ float fdot2f(h2v a, h2v b, float c) {
#if __has_builtin(__builtin_amdgcn_fdot2)
    return __builtin_amdgcn_fdot2(a, b, c, false);
#else
    return c + (float)a[0] * (float)b[0] + (float)a[1] * (float)b[1];
#endif
}

// ---------------------------------------------------------------------------
// prep_u: U [256 x 1024] f32 row-major -> packed half2 per (k-pair, col)
// Uf[k2*1024 + col] = (U[2k2][col], U[2k2+1][col]) as 2xf16 in a uint
// ---------------------------------------------------------------------------
__global__ __launch_bounds__(256) void prep_u(const float* __restrict__ U,
                                              unsigned int* __restrict__ Uf) {
    int idx = blockIdx.x * 256 + threadIdx.x;  // < 131072
    int k2 = idx >> 10, col = idx & 1023;
    union { _Float16 h[2]; unsigned int u; } p;
    p.h[0] = (_Float16)U[(2 * k2) * 1024 + col];
    p.h[1] = (_Float16)U[(2 * k2 + 1) * 1024 + col];
    Uf[idx] = p.u;
}

// ---------------------------------------------------------------------------
// Generic f32 GEMM: C[M,N] = opA(A)[M,K] @ B[K,N] + bias[N]
// ---------------------------------------------------------------------------
__global__ __launch_bounds__(256) void gemm_bias(const float* __restrict__ A,
                                                 const float* __restrict__ B,
                                                 const float* __restrict__ bias,
                                                 float* __restrict__ C,
                                                 int M, int N, int K, int revA) {
    __shared__ float sA[16][65];
    __shared__ float sB[16][65];
    int tid = threadIdx.x;
    int bm = blockIdx.y * 64, bn = blockIdx.x * 64;
    int tx = tid & 15, ty = tid >> 4;
    float acc[4][4] = {};
    for (int k0 = 0; k0 < K; k0 += 16) {
#pragma unroll
        for (int l = 0; l < 4; l++) {
            int flat = tid + 256 * l;
            int ml = flat >> 4, kk = flat & 15;
            int row = bm + ml;
            if (revA) row = M - 1 - row;
            sA[kk][ml] = A[row * K + k0 + kk];
        }
#pragma unroll
        for (int l = 0; l < 4; l++) {
            int flat = tid + 256 * l;
            int kk = flat >> 6, nl = flat & 63;
            sB[kk][nl] = B[(k0 + kk) * N + bn + nl];
        }
        __syncthreads();
#pragma unroll
        for (int kk = 0; kk < 16; kk++) {
            float a[4], b[4];
#pragma unroll
            for (int i = 0; i < 4; i++) a[i] = sA[kk][ty + 16 * i];
#pragma unroll
            for (int j = 0; j < 4; j++) b[j] = sB[kk][tx + 16 * j];
#pragma unroll
            for (int i = 0; i < 4; i++)
#pragma unroll
                for (int j = 0; j < 4; j++) acc[i][j] += a[i] * b[j];
        }
        __syncthreads();
    }
#pragma unroll
    for (int i = 0; i < 4; i++) {
        int r = bm + ty + 16 * i;
#pragma unroll
        for (int j = 0; j < 4; j++) {
            int cidx = bn + tx + 16 * j;
            float bv = bias ? bias[cidx] : 0.f;
            C[r * N + cidx] = acc[i][j] + bv;
        }
    }
}

// ---------------------------------------------------------------------------
// lstm_two: 2 blocks (fwd, bwd), 512 threads, 1 block/CU. DETERMINISTIC --
// no cross-block sync (rounds 4-9 verdict: agent-atomic exchange floors at
// ~2us/step at the LLC, the sc0 same-XCD fast channel never propagates
// between CUs [r9: 13us/step = exactly 128 failed sc0 polls], and spin-sync
// nondeterminism produced 20-47ms outliers + 2 container deaths).
//
// Hybrid residency sized to the MEASURED allocator law (grant = 128 VGPR
// @512thr, independent of waves_per_eu; pinning beyond the grant => total
// spill, r1/r3):
//   kp [ 0,36): LDS, k-major (144KB)
//   kp [36,68): registers, 4 x u32x8 per column = 64 VGPRs pinned
//               (64 + ~30 core + ~30 load-pipeline ~= 124 <= 128: fits,
//               unlike r3's 80-pin which forced total spill)
//   kp [68,128): streamed from L2 each step -- 60 kp = 240KB/step of pure
//               h-independent weight stream, deep-pipelined by the compiler.
// Roofline: 240KB/step @ ~67B/cyc/CU L2 fill = ~3.7Kcy = 1.55us/step
// -> ~790us/dispatch (vs 1163 r0 full-stream, 961 r7 duo-sync).
// ---------------------------------------------------------------------------
#define KLDS 36
#define KREG 32

// constant-index select across the four 8-wide vectors; folds at -O3
#define UA(r) ((r) < 8 ? qa0[(r) & 7] : (r) < 16 ? qa1[(r) & 7] : \
               (r) < 24 ? qa2[(r) & 7] : qa3[(r) & 7])
#define UB(r) ((r) < 8 ? qb0[(r) & 7] : (r) < 16 ? qb1[(r) & 7] : \
               (r) < 24 ? qb2[(r) & 7] : qb3[(r) & 7])

#define LOADQ(qi, va, vb)                                                      \
    do {                                                                       \
        _Pragma("unroll") for (int j = 0; j < 8; j++) {                        \
            uint2 w = *(const uint2*)&U[(KLDS + 8 * (qi) + j) * 1024 + 2 * t]; \
            va[j] = w.x;                                                       \
            vb[j] = w.y;                                                       \
        }                                                                      \
    } while (0)

__global__ __attribute__((amdgpu_flat_work_group_size(512, 512)))
void lstm_two(
        const unsigned int* __restrict__ Ua, const unsigned int* __restrict__ Ub,
        const float* __restrict__ Pa, const float* __restrict__ Pb,
        float* __restrict__ Oa, float* __restrict__ Ob) {
    const unsigned int* U = blockIdx.x ? Ub : Ua;
    const float* P = blockIdx.x ? Pb : Pa;
    float* O = blockIdx.x ? Ob : Oa;

    __shared__ unsigned int sU[KLDS * 1024];        // 147456 B, k-major
    __shared__ __align__(16) _Float16 sH[256];      // 512 B
    __shared__ float sZ[1024];                      // 4096 B

    int t = threadIdx.x;  // 0..511, owns columns 2t and 2t+1

    // stage LDS-resident k-pairs of U (k-major: sU[kp*1024 + col])
    for (int i = t; i < KLDS * 1024; i += 512) sU[i] = U[i];

    // register-resident kp [36,68): 8 x 8-wide SSA vectors = 64 VGPRs
    u32x8 qa0, qa1, qa2, qa3;
    u32x8 qb0, qb1, qb2, qb3;
    LOADQ(0, qa0, qb0);
    LOADQ(1, qa1, qb1);
    LOADQ(2, qa2, qb2);
    LOADQ(3, qa3, qb3);

    // keep resident values opaque (non-rematerializable)
    asm volatile(""
                 : "+v"(qa0), "+v"(qa1), "+v"(qa2), "+v"(qa3),
                   "+v"(qb0), "+v"(qb1), "+v"(qb2), "+v"(qb3));

    float c = 0.f;
    if (t < 256) sH[t] = (_Float16)0.f;
    __syncthreads();

    const uint4* hp4 = (const uint4*)sH;  // 32 chunks x (4 h2v) = 256 h
    float2 pc = *(const float2*)(P + 2 * t);
    for (int step = 0; step < 512; step++) {
        float2 pn = pc;
        if (step < 511) pn = *(const float2*)(P + (step + 1) * 1024 + 2 * t);
        float acc0 = pc.x, acc1 = pc.y;  // two cols = two indep dep-chains

        // --- kp [0,36) from LDS: h via b128 broadcast, U via b64 (2-way=free)
#pragma unroll
        for (int cch = 0; cch < 9; cch++) {
            uint4 hc = hp4[cch];
            const unsigned int* su = &sU[(4 * cch) * 1024 + 2 * t];
            uint2 w;
            w = *(const uint2*)(su);
            acc0 = fdot2f(BC(hc.x), BC(w.x), acc0);
            acc1 = fdot2f(BC(hc.x), BC(w.y), acc1);
            w = *(const uint2*)(su + 1024);
            acc0 = fdot2f(BC(hc.y), BC(w.x), acc0);
            acc1 = fdot2f(BC(hc.y), BC(w.y), acc1);
            w = *(const uint2*)(su + 2048);
            acc0 = fdot2f(BC(hc.z), BC(w.x), acc0);
            acc1 = fdot2f(BC(hc.z), BC(w.y), acc1);
            w = *(const uint2*)(su + 3072);
            acc0 = fdot2f(BC(hc.w), BC(w.x), acc0);
            acc1 = fdot2f(BC(hc.w), BC(w.y), acc1);
        }
        // --- kp [36,68) from registers
#pragma unroll
        for (int cch = 9; cch < 17; cch++) {
            uint4 hc = hp4[cch];
            const int r0 = 4 * (cch - 9);
            acc0 = fdot2f(BC(hc.x), BC(UA(r0 + 0)), acc0);
            acc1 = fdot2f(BC(hc.x), BC(UB(r0 + 0)), acc1);
            acc0 = fdot2f(BC(hc.y), BC(UA(r0 + 1)), acc0);
            acc1 = fdot2f(BC(hc.y), BC(UB(r0 + 1)), acc1);
            acc0 = fdot2f(BC(hc.z), BC(UA(r0 + 2)), acc0);
            acc1 = fdot2f(BC(hc.z), BC(UB(r0 + 2)), acc1);
            acc0 = fdot2f(BC(hc.w), BC(UA(r0 + 3)), acc0);
            acc1 = fdot2f(BC(hc.w), BC(UB(r0 + 3)), acc1);
        }
        // --- kp [68,128) streamed from L2: h-independent coalesced uint2
        // loads, unrolled so the compiler keeps a deep vmcnt pipeline.
#pragma unroll
        for (int cch = 17; cch < 32; cch++) {
            uint4 hc = hp4[cch];
            const unsigned int* ug = &U[(4 * cch) * 1024 + 2 * t];
            uint2 w0 = *(const uint2*)(ug);
            uint2 w1 = *(const uint2*)(ug + 1024);
            uint2 w2 = *(const uint2*)(ug + 2048);
            uint2 w3 = *(const uint2*)(ug + 3072);
            acc0 = fdot2f(BC(hc.x), BC(w0.x), acc0);
            acc1 = fdot2f(BC(hc.x), BC(w0.y), acc1);
            acc0 = fdot2f(BC(hc.y), BC(w1.x), acc0);
            acc1 = fdot2f(BC(hc.y), BC(w1.y), acc1);
            acc0 = fdot2f(BC(hc.z), BC(w2.x), acc0);
            acc1 = fdot2f(BC(hc.z), BC(w2.y), acc1);
            acc0 = fdot2f(BC(hc.w), BC(w3.x), acc0);
            acc1 = fdot2f(BC(hc.w), BC(w3.y), acc1);
        }
        ((float2*)sZ)[t] = make_float2(acc0, acc1);
        __syncthreads();
        if (t < 256) {
            float zi = sZ[t], zf = sZ[256 + t], zg = sZ[512 + t], zo = sZ[768 + t];
            float ig = 1.f / (1.f + __expf(-zi));
            float fg = 1.f / (1.f + __expf(-zf));
            float gg = 1.f - 2.f / (1.f + __expf(2.f * zg));   // tanh
            float og = 1.f / (1.f + __expf(-zo));
            c = fg * c + ig * gg;
            float h = og * (1.f - 2.f / (1.f + __expf(2.f * c)));
            O[step * 256 + t] = h;
            sH[t] = (_Float16)h;
        }
        __syncthreads();
        pc = pn;
    }
}

// ---------------------------------------------------------------------------
// concat: V[t][0:256] = F[t], V[t][256:512] = Bk[511-t]
// ---------------------------------------------------------------------------
__global__ __launch_bounds__(256) void concat_k(const float* __restrict__ F,
                                                const float* __restrict__ Bk,
                                                float* __restrict__ V) {
    int idx = blockIdx.x * 256 + threadIdx.x;  // < 262144
    int t = idx >> 9, d = idx & 511;
    V[idx] = (d < 256) ? F[t * 256 + d] : Bk[(511 - t) * 256 + d - 256];
}

// ---------------------------------------------------------------------------
// head: S[i][j] = sum_h tanh(HF[i][h] + MF[j][h]) * w[h] + outBias
// ---------------------------------------------------------------------------
__global__ __launch_bounds__(256) void head_kernel(const float* __restrict__ HF,
                                                   const float* __restrict__ MF,
                                                   const float* __restrict__ w,
                                                   const float* __restrict__ outb,
                                                   float* __restrict__ S) {
    int i = blockIdx.x;
    __shared__ float sHF[512], sW[512];
    int tid = threadIdx.x;
    sHF[tid] = HF[i * 512 + tid];
    sHF[tid + 256] = HF[i * 512 + 256 + tid];
    sW[tid] = w[tid];
    sW[tid + 256] = w[tid + 256];
    __syncthreads();
    int lane = tid & 63, wv = tid >> 6;
    float ob = outb[0];
    for (int j = wv; j < 512; j += 4) {
        const float* mf = MF + j * 512;
        float acc = 0.f;
#pragma unroll
        for (int r = 0; r < 8; r++) {
            int h = lane + 64 * r;
            float x = sHF[h] + mf[h];
            acc += sW[h] * (1.f - 2.f / (1.f + __expf(2.f * x)));
        }
#pragma unroll
        for (int off = 32; off; off >>= 1) acc += __shfl_down(acc, off);
        if (lane == 0) S[i * 512 + j] = acc + ob;
    }
}

// ---------------------------------------------------------------------------
extern "C" void kernel_launch(void* const* d_in, const int* in_sizes, int n_in,
                              void* d_out, int out_size, void* d_ws, size_t ws_size,
                              hipStream_t stream) {
    const float* emb      = (const float*)d_in[0];
    const float* W_f1     = (const float*)d_in[1];
    const float* U_f1     = (const float*)d_in[2];
    const float* b_f1     = (const float*)d_in[3];
    const float* W_b1     = (const float*)d_in[4];
    const float* U_b1     = (const float*)d_in[5];
    const float* b_b1     = (const float*)d_in[6];
    const float* W_f2     = (const float*)d_in[7];
    const float* U_f2     = (const float*)d_in[8];
    const float* b_f2     = (const float*)d_in[9];
    const float* W_b2     = (const float*)d_in[10];
    const float* U_b2     = (const float*)d_in[11];
    const float* b_b2     = (const float*)d_in[12];
    const float* FOH      = (const float*)d_in[13];
    const float* FOM      = (const float*)d_in[14];
    const float* hidBias  = (const float*)d_in[15];
    const float* outLayer = (const float*)d_in[16];
    const float* outBias  = (const float*)d_in[17];
    float* out = (float*)d_out;

    // workspace carve (16 MB total)
    unsigned int* uf = (unsigned int*)d_ws;          // 4 x 131072 uints = 2MB
    unsigned int* uf_f1 = uf;
    unsigned int* uf_b1 = uf + 131072;
    unsigned int* uf_f2 = uf + 262144;
    unsigned int* uf_b2 = uf + 393216;
    float* f = (float*)d_ws + 524288;
    float* P1f = f;                 // 512x1024
    float* P1b = f + 524288;
    float* P2f = f + 1048576;
    float* P2b = f + 1572864;
    float* rf1 = f + 2097152;       // 512x256
    float* rb1 = f + 2228224;
    float* rf2 = f + 2359296;
    float* rb2 = f + 2490368;
    float* v    = f + 2621440;      // 512x512
    float* hcat = f + 2883584;
    float* HFb  = f + 3145728;      // 512x512 (includes hidBias)
    float* MFb  = f + 3407872;

    prep_u<<<512, 256, 0, stream>>>(U_f1, uf_f1);
    prep_u<<<512, 256, 0, stream>>>(U_b1, uf_b1);
    prep_u<<<512, 256, 0, stream>>>(U_f2, uf_f2);
    prep_u<<<512, 256, 0, stream>>>(U_b2, uf_b2);

    dim3 g1(1024 / 64, 512 / 64);
    gemm_bias<<<g1, 256, 0, stream>>>(emb, W_f1, b_f1, P1f, 512, 1024, 256, 0);
    gemm_bias<<<g1, 256, 0, stream>>>(emb, W_b1, b_b1, P1b, 512, 1024, 256, 1);

    lstm_two<<<2, 512, 0, stream>>>(uf_f1, uf_b1, P1f, P1b, rf1, rb1);

    concat_k<<<1024, 256, 0, stream>>>(rf1, rb1, v);

    gemm_bias<<<g1, 256, 0, stream>>>(v, W_f2, b_f2, P2f, 512, 1024, 512, 0);
    gemm_bias<<<g1, 256, 0, stream>>>(v, W_b2, b_b2, P2b, 512, 1024, 512, 1);

    lstm_two<<<2, 512, 0, stream>>>(uf_f2, uf_b2, P2f, P2b, rf2, rb2);

    concat_k<<<1024, 256, 0, stream>>>(rf2, rb2, hcat);

    dim3 g2(512 / 64, 512 / 64);
    gemm_bias<<<g2, 256, 0, stream>>>(hcat, FOH, hidBias, HFb, 512, 512, 512, 0);
    gemm_bias<<<g2, 256, 0, stream>>>(hcat, FOM, nullptr, MFb, 512, 512, 512, 0);

    head_kernel<<<512, 256, 0, stream>>>(HFb, MFb, outLayer, outBias, out);
}

// Round 13
// 2512.674 us; speedup vs baseline: 5.4431x; 1.1317x over previous
//
#include <hip/hip_runtime.h>
#include <hip/hip_bf16.h>

// Sizes (fixed): T=512 tokens, D=256 embed, L=256 lstm, H=512 hidden. 4L=1024.

typedef _Float16 h2v __attribute__((ext_vector_type(2)));
typedef unsigned int u32x8 __attribute__((ext_vector_type(8)));

#define BC(x) __builtin_bit_cast(h2v, (x))

__device__ __forceinline__ float fdot2f(h2v a, h2v b, float c) {
#if __has_builtin(__builtin_amdgcn_fdot2)
    return __builtin_amdgcn_fdot2(a, b, c, false);
#else
    return c + (float)a[0] * (float)b[0] + (float)a[1] * (float)b[1];
#endif
}

// ---------------------------------------------------------------------------
// prep_u: U [256 x 1024] f32 row-major -> packed half2 per (k-pair, col)
// Uf[k2*1024 + col] = (U[2k2][col], U[2k2+1][col]) as 2xf16 in a uint
// ---------------------------------------------------------------------------
__global__ __launch_bounds__(256) void prep_u(const float* __restrict__ U,
                                              unsigned int* __restrict__ Uf) {
    int idx = blockIdx.x * 256 + threadIdx.x;  // < 131072
    int k2 = idx >> 10, col = idx & 1023;
    union { _Float16 h[2]; unsigned int u; } p;
    p.h[0] = (_Float16)U[(2 * k2) * 1024 + col];
    p.h[1] = (_Float16)U[(2 * k2 + 1) * 1024 + col];
    Uf[idx] = p.u;
}

// ---------------------------------------------------------------------------
// Generic f32 GEMM: C[M,N] = opA(A)[M,K] @ B[K,N] + bias[N]
// ---------------------------------------------------------------------------
__global__ __launch_bounds__(256) void gemm_bias(const float* __restrict__ A,
                                                 const float* __restrict__ B,
                                                 const float* __restrict__ bias,
                                                 float* __restrict__ C,
                                                 int M, int N, int K, int revA) {
    __shared__ float sA[16][65];
    __shared__ float sB[16][65];
    int tid = threadIdx.x;
    int bm = blockIdx.y * 64, bn = blockIdx.x * 64;
    int tx = tid & 15, ty = tid >> 4;
    float acc[4][4] = {};
    for (int k0 = 0; k0 < K; k0 += 16) {
#pragma unroll
        for (int l = 0; l < 4; l++) {
            int flat = tid + 256 * l;
            int ml = flat >> 4, kk = flat & 15;
            int row = bm + ml;
            if (revA) row = M - 1 - row;
            sA[kk][ml] = A[row * K + k0 + kk];
        }
#pragma unroll
        for (int l = 0; l < 4; l++) {
            int flat = tid + 256 * l;
            int kk = flat >> 6, nl = flat & 63;
            sB[kk][nl] = B[(k0 + kk) * N + bn + nl];
        }
        __syncthreads();
#pragma unroll
        for (int kk = 0; kk < 16; kk++) {
            float a[4], b[4];
#pragma unroll
            for (int i = 0; i < 4; i++) a[i] = sA[kk][ty + 16 * i];
#pragma unroll
            for (int j = 0; j < 4; j++) b[j] = sB[kk][tx + 16 * j];
#pragma unroll
            for (int i = 0; i < 4; i++)
#pragma unroll
                for (int j = 0; j < 4; j++) acc[i][j] += a[i] * b[j];
        }
        __syncthreads();
    }
#pragma unroll
    for (int i = 0; i < 4; i++) {
        int r = bm + ty + 16 * i;
#pragma unroll
        for (int j = 0; j < 4; j++) {
            int cidx = bn + tx + 16 * j;
            float bv = bias ? bias[cidx] : 0.f;
            C[r * N + cidx] = acc[i][j] + bv;
        }
    }
}

// ---------------------------------------------------------------------------
// lstm_quad: 8 blocks (4 per direction) x 256 threads. BYTE-IDENTICAL to the
// round-5 kernel that PASSED at total 2420us (lstm 1032us/dispatch).
//
// Round-12 isolation: r12 = this + s_sleep(1) in the poll loop -> container
// died twice. Deterministic kernels are 6/6 completions this session; spin
// kernels 4/7. Resubmitting the exact verified artifact isolates the delta:
// pass => r5 result reproducible (and s_sleep implicated); die => infra
// indicted, fall back to deterministic r10 next.
//
// Design: block b owns hidden units [64b,64b+64) and all four gate columns
// (col = 256*gate + 64*b + u). U-slice = 128kp x 256 cols: kp[0,64) in LDS
// (64KB), kp[64,128) in 8 x u32x8 = 64 VGPRs (VGPR_Count=88, holds; the
// only pin size/thread-count combo verified to hold all session).
// Nothing streams from L2 in the step loop. Exchange: each h-pair publishes
// as ONE 8-byte relaxed agent-scope atomic {tag=step+1 | packed f16 pair}
// in a parity-double-buffered slot; readers poll their own entry until the
// tag matches -- tag+data in the same load, no fences, no invalidation.
// Parity safety: a writer reuses a slot 2 steps later, and writing tag s+2
// proves (via its own poll of peers' s+2 tags) every peer consumed s+1.
// Stale tags zeroed by 4KB memset per dispatch; bench-loop replays see
// stale-but-identical values (deterministic inputs) which is benign.
// ---------------------------------------------------------------------------
#define UAq(r) ((r) < 8 ? q0[(r) & 7] : (r) < 16 ? q1[(r) & 7] : \
                (r) < 24 ? q2[(r) & 7] : (r) < 32 ? q3[(r) & 7] : \
                (r) < 40 ? q4[(r) & 7] : (r) < 48 ? q5[(r) & 7] : \
                (r) < 56 ? q6[(r) & 7] : q7[(r) & 7])

__global__ __launch_bounds__(256) void lstm_quad(
        const unsigned int* __restrict__ Ua, const unsigned int* __restrict__ Ub,
        const float* __restrict__ Pa, const float* __restrict__ Pb,
        float* __restrict__ Oa, float* __restrict__ Ob,
        unsigned long long* Hg) {
    int dir = blockIdx.x >> 2;  // 0 = fwd, 1 = bwd
    int b = blockIdx.x & 3;     // owns hidden units [64b, 64b+64)
    const unsigned int* U = dir ? Ub : Ua;
    const float* P = dir ? Pb : Pa;
    float* O = dir ? Ob : Oa;
    // per dir: 2 parity buffers x 128 entries (4 blocks x 32 h-pairs)
    unsigned long long* Hgd = Hg + dir * 256;

    __shared__ unsigned int sU[64 * 256];            // 65536 B, kp-major slice
    __shared__ __align__(16) unsigned int sH[128];   // h as packed f16 pairs
    __shared__ float sZ[256];
    __shared__ float sG[64];

    int t = threadIdx.x;  // 0..255
    // gate g = t>>6, unit u = t&63; global column in the 4L z-vector:
    int col = ((t >> 6) << 8) + (b << 6) + (t & 63);

    // stage kp [0,64) of this block's 256 columns into LDS
    for (int kp = 0; kp < 64; kp++) sU[kp * 256 + t] = U[kp * 1024 + col];

    // kp [64,128) register-resident: 8 x 8-wide SSA vectors = 64 VGPRs
    u32x8 q0, q1, q2, q3, q4, q5, q6, q7;
#pragma unroll
    for (int j = 0; j < 8; j++) {
        q0[j] = U[(64 + j) * 1024 + col];
        q1[j] = U[(72 + j) * 1024 + col];
        q2[j] = U[(80 + j) * 1024 + col];
        q3[j] = U[(88 + j) * 1024 + col];
        q4[j] = U[(96 + j) * 1024 + col];
        q5[j] = U[(104 + j) * 1024 + col];
        q6[j] = U[(112 + j) * 1024 + col];
        q7[j] = U[(120 + j) * 1024 + col];
    }
    asm volatile(""
                 : "+v"(q0), "+v"(q1), "+v"(q2), "+v"(q3),
                   "+v"(q4), "+v"(q5), "+v"(q6), "+v"(q7));

    if (t < 128) sH[t] = 0u;
    float c = 0.f;
    __syncthreads();

    const uint4* hp4 = (const uint4*)sH;  // 32 chunks x (4 h2v) = 256 h
    float pc = P[col];
    for (int step = 0; step < 512; step++) {
        float pn = pc;
        if (step < 511) pn = P[(step + 1) * 1024 + col];
        float a0 = pc, a1 = 0.f, a2 = 0.f, a3 = 0.f;  // 4 indep dep-chains

        // kp [0,64) from LDS (lane-consecutive b32, conflict-free)
#pragma unroll
        for (int cch = 0; cch < 16; cch++) {
            uint4 hc = hp4[cch];
            const unsigned int* su = &sU[(4 * cch) * 256 + t];
            a0 = fdot2f(BC(hc.x), BC(su[0]), a0);
            a1 = fdot2f(BC(hc.y), BC(su[256]), a1);
            a2 = fdot2f(BC(hc.z), BC(su[512]), a2);
            a3 = fdot2f(BC(hc.w), BC(su[768]), a3);
        }
        // kp [64,128) from registers
#pragma unroll
        for (int cch = 16; cch < 32; cch++) {
            uint4 hc = hp4[cch];
            const int r0 = 4 * (cch - 16);
            a0 = fdot2f(BC(hc.x), BC(UAq(r0 + 0)), a0);
            a1 = fdot2f(BC(hc.y), BC(UAq(r0 + 1)), a1);
            a2 = fdot2f(BC(hc.z), BC(UAq(r0 + 2)), a2);
            a3 = fdot2f(BC(hc.w), BC(UAq(r0 + 3)), a3);
        }
        sZ[t] = (a0 + a1) + (a2 + a3);
        __syncthreads();

        unsigned long long* Hbuf = Hgd + ((step + 1) & 1) * 128;  // parity
        unsigned long long tag = (unsigned long long)(step + 1);
        if (t < 64) {
            float zi = sZ[t], zf = sZ[64 + t], zg = sZ[128 + t], zo = sZ[192 + t];
            float ig = 1.f / (1.f + __expf(-zi));
            float fg = 1.f / (1.f + __expf(-zf));
            float gg = 1.f - 2.f / (1.f + __expf(2.f * zg));   // tanh
            float og = 1.f / (1.f + __expf(-zo));
            c = fg * c + ig * gg;
            float h = og * (1.f - 2.f / (1.f + __expf(2.f * c)));
            O[step * 256 + (b << 6) + t] = h;
            sG[t] = h;  // wave 0 only: LDS ops below are same-wave ordered
            if (t < 32) {
                union { _Float16 hh[2]; unsigned int u; } pk;
                pk.hh[0] = (_Float16)sG[2 * t];
                pk.hh[1] = (_Float16)sG[2 * t + 1];
                unsigned long long v = (tag << 32) | (unsigned long long)pk.u;
                __hip_atomic_store(&Hbuf[(b << 5) + t], v, __ATOMIC_RELAXED,
                                   __HIP_MEMORY_SCOPE_AGENT);
            }
        }
        // single-round-trip poll: tag+data arrive in the same 8B load
        if (t < 128) {
            unsigned long long v;
            do {
                v = __hip_atomic_load(&Hbuf[t], __ATOMIC_RELAXED,
                                      __HIP_MEMORY_SCOPE_AGENT);
            } while ((v >> 32) != tag);
            sH[t] = (unsigned int)v;
        }
        __syncthreads();
        pc = pn;
    }
}

// ---------------------------------------------------------------------------
// concat: V[t][0:256] = F[t], V[t][256:512] = Bk[511-t]
// ---------------------------------------------------------------------------
__global__ __launch_bounds__(256) void concat_k(const float* __restrict__ F,
                                                const float* __restrict__ Bk,
                                                float* __restrict__ V) {
    int idx = blockIdx.x * 256 + threadIdx.x;  // < 262144
    int t = idx >> 9, d = idx & 511;
    V[idx] = (d < 256) ? F[t * 256 + d] : Bk[(511 - t) * 256 + d - 256];
}

// ---------------------------------------------------------------------------
// head: S[i][j] = sum_h tanh(HF[i][h] + MF[j][h]) * w[h] + outBias
// ---------------------------------------------------------------------------
__global__ __launch_bounds__(256) void head_kernel(const float* __restrict__ HF,
                                                   const float* __restrict__ MF,
                                                   const float* __restrict__ w,
                                                   const float* __restrict__ outb,
                                                   float* __restrict__ S) {
    int i = blockIdx.x;
    __shared__ float sHF[512], sW[512];
    int tid = threadIdx.x;
    sHF[tid] = HF[i * 512 + tid];
    sHF[tid + 256] = HF[i * 512 + 256 + tid];
    sW[tid] = w[tid];
    sW[tid + 256] = w[tid + 256];
    __syncthreads();
    int lane = tid & 63, wv = tid >> 6;
    float ob = outb[0];
    for (int j = wv; j < 512; j += 4) {
        const float* mf = MF + j * 512;
        float acc = 0.f;
#pragma unroll
        for (int r = 0; r < 8; r++) {
            int h = lane + 64 * r;
            float x = sHF[h] + mf[h];
            acc += sW[h] * (1.f - 2.f / (1.f + __expf(2.f * x)));
        }
#pragma unroll
        for (int off = 32; off; off >>= 1) acc += __shfl_down(acc, off);
        if (lane == 0) S[i * 512 + j] = acc + ob;
    }
}

// ---------------------------------------------------------------------------
extern "C" void kernel_launch(void* const* d_in, const int* in_sizes, int n_in,
                              void* d_out, int out_size, void* d_ws, size_t ws_size,
                              hipStream_t stream) {
    const float* emb      = (const float*)d_in[0];
    const float* W_f1     = (const float*)d_in[1];
    const float* U_f1     = (const float*)d_in[2];
    const float* b_f1     = (const float*)d_in[3];
    const float* W_b1     = (const float*)d_in[4];
    const float* U_b1     = (const float*)d_in[5];
    const float* b_b1     = (const float*)d_in[6];
    const float* W_f2     = (const float*)d_in[7];
    const float* U_f2     = (const float*)d_in[8];
    const float* b_f2     = (const float*)d_in[9];
    const float* W_b2     = (const float*)d_in[10];
    const float* U_b2     = (const float*)d_in[11];
    const float* b_b2     = (const float*)d_in[12];
    const float* FOH      = (const float*)d_in[13];
    const float* FOM      = (const float*)d_in[14];
    const float* hidBias  = (const float*)d_in[15];
    const float* outLayer = (const float*)d_in[16];
    const float* outBias  = (const float*)d_in[17];
    float* out = (float*)d_out;

    // workspace carve (16 MB total)
    unsigned int* uf = (unsigned int*)d_ws;          // 4 x 131072 uints = 2MB
    unsigned int* uf_f1 = uf;
    unsigned int* uf_b1 = uf + 131072;
    unsigned int* uf_f2 = uf + 262144;
    unsigned int* uf_b2 = uf + 393216;
    float* f = (float*)d_ws + 524288;
    float* P1f = f;                 // 512x1024
    float* P1b = f + 524288;
    float* P2f = f + 1048576;
    float* P2b = f + 1572864;
    float* rf1 = f + 2097152;       // 512x256
    float* rb1 = f + 2228224;
    float* rf2 = f + 2359296;
    float* rb2 = f + 2490368;
    float* v    = f + 2621440;      // 512x512
    float* hcat = f + 2883584;
    float* HFb  = f + 3145728;      // 512x512 (includes hidBias)
    float* MFb  = f + 3407872;
    // sync region aliases MFb (dead during both lstm dispatches: MFb is only
    // written by the 2nd-to-last gemm and read by head, both after lstm-2).
    // 2 dirs x 2 parity x 128 tagged 8B entries = 4KB.
    unsigned long long* sync = (unsigned long long*)(f + 3407872);

    prep_u<<<512, 256, 0, stream>>>(U_f1, uf_f1);
    prep_u<<<512, 256, 0, stream>>>(U_b1, uf_b1);
    prep_u<<<512, 256, 0, stream>>>(U_f2, uf_f2);
    prep_u<<<512, 256, 0, stream>>>(U_b2, uf_b2);

    dim3 g1(1024 / 64, 512 / 64);
    gemm_bias<<<g1, 256, 0, stream>>>(emb, W_f1, b_f1, P1f, 512, 1024, 256, 0);
    gemm_bias<<<g1, 256, 0, stream>>>(emb, W_b1, b_b1, P1b, 512, 1024, 256, 1);

    hipMemsetAsync(sync, 0, 4096, stream);
    lstm_quad<<<8, 256, 0, stream>>>(uf_f1, uf_b1, P1f, P1b, rf1, rb1, sync);

    concat_k<<<1024, 256, 0, stream>>>(rf1, rb1, v);

    gemm_bias<<<g1, 256, 0, stream>>>(v, W_f2, b_f2, P2f, 512, 1024, 512, 0);
    gemm_bias<<<g1, 256, 0, stream>>>(v, W_b2, b_b2, P2b, 512, 1024, 512, 1);

    hipMemsetAsync(sync, 0, 4096, stream);
    lstm_quad<<<8, 256, 0, stream>>>(uf_f2, uf_b2, P2f, P2b, rf2, rb2, sync);

    concat_k<<<1024, 256, 0, stream>>>(rf2, rb2, hcat);

    dim3 g2(512 / 64, 512 / 64);
    gemm_bias<<<g2, 256, 0, stream>>>(hcat, FOH, hidBias, HFb, 512, 512, 512, 0);
    gemm_bias<<<g2, 256, 0, stream>>>(hcat, FOM, nullptr, MFb, 512, 512, 512, 0);

    head_kernel<<<512, 256, 0, stream>>>(HFb, MFb, outLayer, outBias, out);
}

// Round 14
// 2269.029 us; speedup vs baseline: 6.0275x; 1.1074x over previous
//
#include <hip/hip_runtime.h>
#include <hip/hip_bf16.h>

// Sizes (fixed): T=512 tokens, D=256 embed, L=256 lstm, H=512 hidden. 4L=1024.

typedef _Float16 h2v __attribute__((ext_vector_type(2)));
typedef unsigned int u32x8 __attribute__((ext_vector_type(8)));

#define BC(x) __builtin_bit_cast(h2v, (x))

__device__ __forceinline__ float fdot2f(h2v a, h2v b, float c) {
#if __has_builtin(__builtin_amdgcn_fdot2)
    return __builtin_amdgcn_fdot2(a, b, c, false);
#else
    return c + (float)a[0] * (float)b[0] + (float)a[1] * (float)b[1];
#endif
}

// ---------------------------------------------------------------------------
// prep_u4: all four U matrices in one launch (grid 2048; was 4 x 512 blocks).
// Uf[g*131072 + k2*1024 + col] = (U_g[2k2][col], U_g[2k2+1][col]) as 2xf16
// ---------------------------------------------------------------------------
__global__ __launch_bounds__(256) void prep_u4(const float* __restrict__ U0,
                                               const float* __restrict__ U1,
                                               const float* __restrict__ U2,
                                               const float* __restrict__ U3,
                                               unsigned int* __restrict__ Uf) {
    int g = blockIdx.x >> 9;  // 0..3
    int idx = (blockIdx.x & 511) * 256 + threadIdx.x;  // < 131072
    const float* U = (g == 0) ? U0 : (g == 1) ? U1 : (g == 2) ? U2 : U3;
    int k2 = idx >> 10, col = idx & 1023;
    union { _Float16 h[2]; unsigned int u; } p;
    p.h[0] = (_Float16)U[(2 * k2) * 1024 + col];
    p.h[1] = (_Float16)U[(2 * k2 + 1) * 1024 + col];
    Uf[g * 131072 + idx] = p.u;
}

// ---------------------------------------------------------------------------
// gemm2: paired f32 GEMM. blockIdx.z selects {B,bias,C,revA}; both halves of
// a layer run CONCURRENTLY (256 blocks fill the 256-CU chip; the old split
// launches ran 128 blocks each, half-idle, sequentially).
// C[M,N] = opA(A)[M,K] @ B[K,N] + bias[N].
// Inner loop: 2 x ds_read_b128 per kp (acc remap r=4ty+i, c=4tx+j); LDS pad
// 68 floats keeps staging writes 2-way (free) and rows 16B-aligned.
// ---------------------------------------------------------------------------
__global__ __launch_bounds__(256) void gemm2(const float* __restrict__ A,
                                             const float* __restrict__ B0,
                                             const float* __restrict__ B1,
                                             const float* __restrict__ bias0,
                                             const float* __restrict__ bias1,
                                             float* __restrict__ C0,
                                             float* __restrict__ C1,
                                             int M, int N, int K, int rev1) {
    const float* B = blockIdx.z ? B1 : B0;
    const float* bias = blockIdx.z ? bias1 : bias0;
    float* C = blockIdx.z ? C1 : C0;
    int revA = blockIdx.z ? rev1 : 0;

    __shared__ __align__(16) float sA[16][68];
    __shared__ __align__(16) float sB[16][68];
    int tid = threadIdx.x;
    int bm = blockIdx.y * 64, bn = blockIdx.x * 64;
    int tx = tid & 15, ty = tid >> 4;
    float acc[4][4] = {};
    for (int k0 = 0; k0 < K; k0 += 16) {
#pragma unroll
        for (int l = 0; l < 4; l++) {
            int flat = tid + 256 * l;
            int ml = flat >> 4, kk = flat & 15;
            int row = bm + ml;
            if (revA) row = M - 1 - row;
            sA[kk][ml] = A[row * K + k0 + kk];
        }
#pragma unroll
        for (int l = 0; l < 4; l++) {
            int flat = tid + 256 * l;
            int kk = flat >> 6, nl = flat & 63;
            sB[kk][nl] = B[(k0 + kk) * N + bn + nl];
        }
        __syncthreads();
#pragma unroll
        for (int kk = 0; kk < 16; kk++) {
            float4 av = *(const float4*)&sA[kk][4 * ty];
            float4 bv = *(const float4*)&sB[kk][4 * tx];
            float a[4] = {av.x, av.y, av.z, av.w};
            float b[4] = {bv.x, bv.y, bv.z, bv.w};
#pragma unroll
            for (int i = 0; i < 4; i++)
#pragma unroll
                for (int j = 0; j < 4; j++) acc[i][j] += a[i] * b[j];
        }
        __syncthreads();
    }
    float4 bb = make_float4(0.f, 0.f, 0.f, 0.f);
    if (bias) bb = *(const float4*)&bias[bn + 4 * tx];
#pragma unroll
    for (int i = 0; i < 4; i++) {
        int r = bm + 4 * ty + i;
        float4 cv = make_float4(acc[i][0] + bb.x, acc[i][1] + bb.y,
                                acc[i][2] + bb.z, acc[i][3] + bb.w);
        *(float4*)&C[r * N + bn + 4 * tx] = cv;
    }
}

// ---------------------------------------------------------------------------
// lstm_quad: 8 blocks (4 per direction) x 256 threads. Compute/sync core is
// BYTE-IDENTICAL to the round-5/round-13 verified kernel (1029us/dispatch,
// passed twice). Single delta: the h store scatters directly into the
// concat layout (fwd: row=step cols [64b,64b+64); bwd: row=511-step cols
// [256+64b,...)), eliminating the concat_k kernels entirely. Same coalesced
// 64-float store per block.
//
// Design: block b owns hidden units [64b,64b+64) and all four gate columns
// (col = 256*gate + 64*b + u). U-slice = 128kp x 256 cols: kp[0,64) in LDS
// (64KB), kp[64,128) in 8 x u32x8 = 64 VGPRs (VGPR_Count=88, holds).
// Exchange: each h-pair publishes as ONE 8B relaxed agent-scope atomic
// {tag=step+1 | packed f16 pair} in a parity-double-buffered slot; readers
// poll their own entry until the tag matches (tag+data in the same load).
// Parity safety: writer reuses a slot 2 steps later and its own poll of
// peers' s+2 tags proves s+1 was consumed. Stale tags zeroed per dispatch.
// ---------------------------------------------------------------------------
#define UAq(r) ((r) < 8 ? q0[(r) & 7] : (r) < 16 ? q1[(r) & 7] : \
                (r) < 24 ? q2[(r) & 7] : (r) < 32 ? q3[(r) & 7] : \
                (r) < 40 ? q4[(r) & 7] : (r) < 48 ? q5[(r) & 7] : \
                (r) < 56 ? q6[(r) & 7] : q7[(r) & 7])

__global__ __launch_bounds__(256) void lstm_quad(
        const unsigned int* __restrict__ Ua, const unsigned int* __restrict__ Ub,
        const float* __restrict__ Pa, const float* __restrict__ Pb,
        float* __restrict__ Ov, unsigned long long* Hg) {
    int dir = blockIdx.x >> 2;  // 0 = fwd, 1 = bwd
    int b = blockIdx.x & 3;     // owns hidden units [64b, 64b+64)
    const unsigned int* U = dir ? Ub : Ua;
    const float* P = dir ? Pb : Pa;
    // per dir: 2 parity buffers x 128 entries (4 blocks x 32 h-pairs)
    unsigned long long* Hgd = Hg + dir * 256;

    __shared__ unsigned int sU[64 * 256];            // 65536 B, kp-major slice
    __shared__ __align__(16) unsigned int sH[128];   // h as packed f16 pairs
    __shared__ float sZ[256];
    __shared__ float sG[64];

    int t = threadIdx.x;  // 0..255
    // gate g = t>>6, unit u = t&63; global column in the 4L z-vector:
    int col = ((t >> 6) << 8) + (b << 6) + (t & 63);

    // stage kp [0,64) of this block's 256 columns into LDS
    for (int kp = 0; kp < 64; kp++) sU[kp * 256 + t] = U[kp * 1024 + col];

    // kp [64,128) register-resident: 8 x 8-wide SSA vectors = 64 VGPRs
    u32x8 q0, q1, q2, q3, q4, q5, q6, q7;
#pragma unroll
    for (int j = 0; j < 8; j++) {
        q0[j] = U[(64 + j) * 1024 + col];
        q1[j] = U[(72 + j) * 1024 + col];
        q2[j] = U[(80 + j) * 1024 + col];
        q3[j] = U[(88 + j) * 1024 + col];
        q4[j] = U[(96 + j) * 1024 + col];
        q5[j] = U[(104 + j) * 1024 + col];
        q6[j] = U[(112 + j) * 1024 + col];
        q7[j] = U[(120 + j) * 1024 + col];
    }
    asm volatile(""
                 : "+v"(q0), "+v"(q1), "+v"(q2), "+v"(q3),
                   "+v"(q4), "+v"(q5), "+v"(q6), "+v"(q7));

    if (t < 128) sH[t] = 0u;
    float c = 0.f;
    __syncthreads();

    const uint4* hp4 = (const uint4*)sH;  // 32 chunks x (4 h2v) = 256 h
    float pc = P[col];
    for (int step = 0; step < 512; step++) {
        float pn = pc;
        if (step < 511) pn = P[(step + 1) * 1024 + col];
        float a0 = pc, a1 = 0.f, a2 = 0.f, a3 = 0.f;  // 4 indep dep-chains

        // kp [0,64) from LDS (lane-consecutive b32, conflict-free)
#pragma unroll
        for (int cch = 0; cch < 16; cch++) {
            uint4 hc = hp4[cch];
            const unsigned int* su = &sU[(4 * cch) * 256 + t];
            a0 = fdot2f(BC(hc.x), BC(su[0]), a0);
            a1 = fdot2f(BC(hc.y), BC(su[256]), a1);
            a2 = fdot2f(BC(hc.z), BC(su[512]), a2);
            a3 = fdot2f(BC(hc.w), BC(su[768]), a3);
        }
        // kp [64,128) from registers
#pragma unroll
        for (int cch = 16; cch < 32; cch++) {
            uint4 hc = hp4[cch];
            const int r0 = 4 * (cch - 16);
            a0 = fdot2f(BC(hc.x), BC(UAq(r0 + 0)), a0);
            a1 = fdot2f(BC(hc.y), BC(UAq(r0 + 1)), a1);
            a2 = fdot2f(BC(hc.z), BC(UAq(r0 + 2)), a2);
            a3 = fdot2f(BC(hc.w), BC(UAq(r0 + 3)), a3);
        }
        sZ[t] = (a0 + a1) + (a2 + a3);
        __syncthreads();

        unsigned long long* Hbuf = Hgd + ((step + 1) & 1) * 128;  // parity
        unsigned long long tag = (unsigned long long)(step + 1);
        if (t < 64) {
            float zi = sZ[t], zf = sZ[64 + t], zg = sZ[128 + t], zo = sZ[192 + t];
            float ig = 1.f / (1.f + __expf(-zi));
            float fg = 1.f / (1.f + __expf(-zf));
            float gg = 1.f - 2.f / (1.f + __expf(2.f * zg));   // tanh
            float og = 1.f / (1.f + __expf(-zo));
            c = fg * c + ig * gg;
            float h = og * (1.f - 2.f / (1.f + __expf(2.f * c)));
            // direct concat-layout store (replaces concat_k):
            // fwd: v[step][64b+t]; bwd: v[511-step][256+64b+t]
            int orow = dir ? (511 - step) : step;
            Ov[orow * 512 + (dir << 8) + (b << 6) + t] = h;
            sG[t] = h;  // wave 0 only: LDS ops below are same-wave ordered
            if (t < 32) {
                union { _Float16 hh[2]; unsigned int u; } pk;
                pk.hh[0] = (_Float16)sG[2 * t];
                pk.hh[1] = (_Float16)sG[2 * t + 1];
                unsigned long long v = (tag << 32) | (unsigned long long)pk.u;
                __hip_atomic_store(&Hbuf[(b << 5) + t], v, __ATOMIC_RELAXED,
                                   __HIP_MEMORY_SCOPE_AGENT);
            }
        }
        // single-round-trip poll: tag+data arrive in the same 8B load
        if (t < 128) {
            unsigned long long v;
            do {
                v = __hip_atomic_load(&Hbuf[t], __ATOMIC_RELAXED,
                                      __HIP_MEMORY_SCOPE_AGENT);
            } while ((v >> 32) != tag);
            sH[t] = (unsigned int)v;
        }
        __syncthreads();
        pc = pn;
    }
}

// ---------------------------------------------------------------------------
// head: S[i][j] = sum_h tanh(HF[i][h] + MF[j][h]) * w[h] + outBias
// ---------------------------------------------------------------------------
__global__ __launch_bounds__(256) void head_kernel(const float* __restrict__ HF,
                                                   const float* __restrict__ MF,
                                                   const float* __restrict__ w,
                                                   const float* __restrict__ outb,
                                                   float* __restrict__ S) {
    int i = blockIdx.x;
    __shared__ float sHF[512], sW[512];
    int tid = threadIdx.x;
    sHF[tid] = HF[i * 512 + tid];
    sHF[tid + 256] = HF[i * 512 + 256 + tid];
    sW[tid] = w[tid];
    sW[tid + 256] = w[tid + 256];
    __syncthreads();
    int lane = tid & 63, wv = tid >> 6;
    float ob = outb[0];
    for (int j = wv; j < 512; j += 4) {
        const float* mf = MF + j * 512;
        float acc = 0.f;
#pragma unroll
        for (int r = 0; r < 8; r++) {
            int h = lane + 64 * r;
            float x = sHF[h] + mf[h];
            acc += sW[h] * (1.f - 2.f / (1.f + __expf(2.f * x)));
        }
#pragma unroll
        for (int off = 32; off; off >>= 1) acc += __shfl_down(acc, off);
        if (lane == 0) S[i * 512 + j] = acc + ob;
    }
}

// ---------------------------------------------------------------------------
extern "C" void kernel_launch(void* const* d_in, const int* in_sizes, int n_in,
                              void* d_out, int out_size, void* d_ws, size_t ws_size,
                              hipStream_t stream) {
    const float* emb      = (const float*)d_in[0];
    const float* W_f1     = (const float*)d_in[1];
    const float* U_f1     = (const float*)d_in[2];
    const float* b_f1     = (const float*)d_in[3];
    const float* W_b1     = (const float*)d_in[4];
    const float* U_b1     = (const float*)d_in[5];
    const float* b_b1     = (const float*)d_in[6];
    const float* W_f2     = (const float*)d_in[7];
    const float* U_f2     = (const float*)d_in[8];
    const float* b_f2     = (const float*)d_in[9];
    const float* W_b2     = (const float*)d_in[10];
    const float* U_b2     = (const float*)d_in[11];
    const float* b_b2     = (const float*)d_in[12];
    const float* FOH      = (const float*)d_in[13];
    const float* FOM      = (const float*)d_in[14];
    const float* hidBias  = (const float*)d_in[15];
    const float* outLayer = (const float*)d_in[16];
    const float* outBias  = (const float*)d_in[17];
    float* out = (float*)d_out;

    // workspace carve (16 MB total)
    unsigned int* uf = (unsigned int*)d_ws;          // 4 x 131072 uints = 2MB
    unsigned int* uf_f1 = uf;
    unsigned int* uf_b1 = uf + 131072;
    unsigned int* uf_f2 = uf + 262144;
    unsigned int* uf_b2 = uf + 393216;
    float* f = (float*)d_ws + 524288;
    float* P1f = f;                 // 512x1024
    float* P1b = f + 524288;
    float* P2f = f + 1048576;
    float* P2b = f + 1572864;
    float* v    = f + 2621440;      // 512x512 (lstm1 writes concat directly)
    float* hcat = f + 2883584;      // 512x512 (lstm2 writes concat directly)
    float* HFb  = f + 3145728;      // 512x512 (includes hidBias)
    float* MFb  = f + 3407872;
    // sync region aliases MFb (dead during both lstm dispatches: MFb is only
    // written by the last gemm2 and read by head, both after lstm-2).
    // 2 dirs x 2 parity x 128 tagged 8B entries = 4KB.
    unsigned long long* sync = (unsigned long long*)(f + 3407872);

    prep_u4<<<2048, 256, 0, stream>>>(U_f1, U_b1, U_f2, U_b2, uf);

    dim3 g1(1024 / 64, 512 / 64, 2);
    gemm2<<<g1, 256, 0, stream>>>(emb, W_f1, W_b1, b_f1, b_b1, P1f, P1b,
                                  512, 1024, 256, 1);

    hipMemsetAsync(sync, 0, 4096, stream);
    lstm_quad<<<8, 256, 0, stream>>>(uf_f1, uf_b1, P1f, P1b, v, sync);

    gemm2<<<g1, 256, 0, stream>>>(v, W_f2, W_b2, b_f2, b_b2, P2f, P2b,
                                  512, 1024, 512, 1);

    hipMemsetAsync(sync, 0, 4096, stream);
    lstm_quad<<<8, 256, 0, stream>>>(uf_f2, uf_b2, P2f, P2b, hcat, sync);

    dim3 g2(512 / 64, 512 / 64, 2);
    gemm2<<<g2, 256, 0, stream>>>(hcat, FOH, FOM, hidBias, nullptr, HFb, MFb,
                                  512, 512, 512, 0);

    head_kernel<<<512, 256, 0, stream>>>(HFb, MFb, outLayer, outBias, out);
}